// Round 3
// 1997.440 us; speedup vs baseline: 1.1152x; 1.1152x over previous
//
#include <hip/hip_runtime.h>
#include <cstdint>
#include <cstddef>

// ---------------------------------------------------------------------------
// myModel_ICDM: 5 two-layer MLPs + 2 pooling GEMMs, all as bf16 MFMA GEMMs.
// Two GEMM kernels, BOTH using only global_load_lds + __syncthreads (no inline
// asm, no raw s_barrier, no setprio — round-0-proven synchronization):
//  - gemm_bt_kernel: m97-style 128x128 tile, XOR k-slot LDS swizzle.
//  - gemm256_2ph_kernel: 256x256 tile, BK=64, 8 waves, 128KiB LDS
//    double-buffer, prefetch-issue-first 2-phase loop (T3 minimum recipe),
//    same XOR swizzle via pre-swizzled global source.
// Routed: A1, D1, EA2, ED2 -> gemm256 (grids exactly 256 blocks = 1/CU).
// ---------------------------------------------------------------------------

typedef unsigned short u16;
typedef unsigned int u32;
typedef __bf16 bf16_t;
typedef bf16_t bf16x8 __attribute__((ext_vector_type(8)));
typedef float f32x4 __attribute__((ext_vector_type(4)));
typedef u16 u16x4 __attribute__((ext_vector_type(4)));
typedef u16 u16x8 __attribute__((ext_vector_type(8)));

__device__ __forceinline__ u16 f2bf(float x) {  // RNE fp32->bf16
  u32 u = __builtin_bit_cast(u32, x);
  u += 0x7FFFu + ((u >> 16) & 1u);
  return (u16)(u >> 16);
}
__device__ __forceinline__ float bf2f(u16 h) {
  u32 u = ((u32)h) << 16;
  return __builtin_bit_cast(float, u);
}

#define AS1(p) ((__attribute__((address_space(1))) void*)(p))
#define AS3(p) ((__attribute__((address_space(3))) void*)(p))

// --------------------------- dtype detection -------------------------------
__global__ void detect_kernel(const u32* __restrict__ p, int* __restrict__ flag) {
  if (threadIdx.x == 0 && blockIdx.x == 0) {
    int cnt = 0;
    for (int i = 0; i < 64; ++i) {
      u32 b = (p[i] >> 8) & 0xFFu;
      cnt += (b >= 0x3Au && b < 0x40u) ? 1 : 0;
    }
    *flag = (cnt >= 32) ? 1 : 0;  // 1 = bf16 inputs/outputs, 0 = fp32
  }
}

// --------------------------- convert (copy) --------------------------------
__global__ void convert_kernel(const void* __restrict__ src, u16* __restrict__ dst,
                               long n, const int* __restrict__ fl) {
  long i = ((long)blockIdx.x * 256 + threadIdx.x) * 8;
  if (i >= n) return;
  u16x8 r;
  if (*fl) {
    r = *(const u16x8*)((const u16*)src + i);
  } else {
    const float* s = (const float*)src + i;
#pragma unroll
    for (int j = 0; j < 8; ++j) r[j] = f2bf(s[j]);
  }
  *(u16x8*)(dst + i) = r;
}

// --------------------------- transpose-convert -----------------------------
__global__ void tconv_kernel(const void* __restrict__ src, long soff, u16* __restrict__ dst,
                             int R, int C, const int* __restrict__ fl) {
  __shared__ u16 t[32][33];
  const int dt = *fl;
  const int tx = threadIdx.x & 31, ty = threadIdx.x >> 5;
  const long c0 = (long)blockIdx.x * 32, r0 = (long)blockIdx.y * 32;
#pragma unroll
  for (int r = 0; r < 4; ++r) {
    int rr = ty * 4 + r;
    long off = soff + (r0 + rr) * (long)C + c0 + tx;
    t[rr][tx] = dt ? ((const u16*)src)[off] : f2bf(((const float*)src)[off]);
  }
  __syncthreads();
#pragma unroll
  for (int r = 0; r < 4; ++r) {
    int rr = ty * 4 + r;
    dst[(c0 + rr) * (long)R + r0 + tx] = t[tx][rr];
  }
}

// --------------------------- split-K reduce --------------------------------
__global__ void reduce4_kernel(const float* __restrict__ s, long stride,
                               u16* __restrict__ dst, long ldd, long n, int cl,
                               const void* __restrict__ bias, int relu,
                               const int* __restrict__ fl) {
  long i = (long)blockIdx.x * 256 + threadIdx.x;
  if (i >= n) return;
  float v = s[i] + s[i + stride] + s[i + 2 * stride] + s[i + 3 * stride];
  long col = i & ((1L << cl) - 1);
  if (bias) v += (*fl) ? bf2f(((const u16*)bias)[col]) : ((const float*)bias)[col];
  if (relu) v = v > 0.f ? v : 0.f;
  dst[(i >> cl) * ldd + col] = f2bf(v);
}

// --------------------------- GEMM 128x128 (m97-style) ----------------------
__global__ __launch_bounds__(256) void gemm_bt_kernel(
    const u16* __restrict__ A, long lda,
    const u16* __restrict__ Bt, long ldb,
    long K,
    const void* __restrict__ bias, int relu,
    void* __restrict__ outd, long odoff, long ldod,
    float* __restrict__ outw, long ldow, long ozstride,
    u16* __restrict__ outb, long ldob,
    u16* __restrict__ outb2, long ldob2,
    u16* __restrict__ outT, long ldT,
    const int* __restrict__ fl) {
  __shared__ u16 As[128 * 32];
  __shared__ u16 Bs[128 * 32];

  const int t = threadIdx.x;
  const int l = t & 63;
  const int w = t >> 6;
  const int wx = w & 1, wy = w >> 1;
  const long m0 = (long)blockIdx.y * 128;
  const long n0 = (long)blockIdx.x * 128;
  const int dt = *fl;

  const long koff = (long)blockIdx.z * K;
  A += koff;
  Bt += koff;
  if (outw) outw += (long)blockIdx.z * ozstride;

  // staging coords: lane loads 16B; XOR k-slot swizzle (slot ^= row&3).
  const int srow = w * 16 + (l >> 2);
  const int scol = (((l & 3) ^ ((l >> 2) & 3))) * 8;
  const int la = l & 15, lq = l >> 4;
  const int fsl = (lq ^ (la & 3)) * 8;  // fragment-read swizzled slot

  f32x4 acc[4][4];
  const f32x4 zero = {0.f, 0.f, 0.f, 0.f};
#pragma unroll
  for (int i = 0; i < 4; ++i)
#pragma unroll
    for (int j = 0; j < 4; ++j) acc[i][j] = zero;

  for (long k0 = 0; k0 < K; k0 += 32) {
#pragma unroll
    for (int r = 0; r < 2; ++r) {
      const u16* ga = A + (m0 + r * 64 + srow) * lda + k0 + scol;
      __builtin_amdgcn_global_load_lds(AS1(ga), AS3(As + (r * 64 + w * 16) * 32), 16, 0, 0);
      const u16* gb = Bt + (n0 + r * 64 + srow) * ldb + k0 + scol;
      __builtin_amdgcn_global_load_lds(AS1(gb), AS3(Bs + (r * 64 + w * 16) * 32), 16, 0, 0);
    }
    __syncthreads();

    bf16x8 af[4], bfr[4];
#pragma unroll
    for (int i = 0; i < 4; ++i) {
      af[i] = *(const bf16x8*)(As + (wy * 64 + i * 16 + la) * 32 + fsl);
      bfr[i] = *(const bf16x8*)(Bs + (wx * 64 + i * 16 + la) * 32 + fsl);
    }
#pragma unroll
    for (int i = 0; i < 4; ++i)
#pragma unroll
      for (int j = 0; j < 4; ++j)
        acc[i][j] = __builtin_amdgcn_mfma_f32_16x16x32_bf16(af[i], bfr[j], acc[i][j], 0, 0, 0);
    __syncthreads();
  }

  const long gr0 = m0 + wy * 64;
  const long gc0 = n0 + wx * 64;
#pragma unroll
  for (int i = 0; i < 4; ++i) {
#pragma unroll
    for (int j = 0; j < 4; ++j) {
      const long gc = gc0 + j * 16 + la;
      const long grb = gr0 + i * 16 + lq * 4;
      float bv = 0.f;
      if (bias) bv = dt ? bf2f(((const u16*)bias)[gc]) : ((const float*)bias)[gc];
      float vv[4];
#pragma unroll
      for (int p = 0; p < 4; ++p) {
        float x = acc[i][j][p] + bv;
        if (relu) x = x > 0.f ? x : 0.f;
        vv[p] = x;
      }
      if (outd) {
        if (dt) {
          u16* o = (u16*)outd + odoff;
#pragma unroll
          for (int p = 0; p < 4; ++p) o[(grb + p) * ldod + gc] = f2bf(vv[p]);
        } else {
          float* o = (float*)outd + odoff;
#pragma unroll
          for (int p = 0; p < 4; ++p) o[(grb + p) * ldod + gc] = vv[p];
        }
      }
      if (outw) {
#pragma unroll
        for (int p = 0; p < 4; ++p) outw[(grb + p) * ldow + gc] = vv[p];
      }
      if (outb) {
#pragma unroll
        for (int p = 0; p < 4; ++p) outb[(grb + p) * ldob + gc] = f2bf(vv[p]);
      }
      if (outb2) {
#pragma unroll
        for (int p = 0; p < 4; ++p) outb2[(grb + p) * ldob2 + gc] = f2bf(vv[p]);
      }
      if (outT) {
        u16x4 pk;
#pragma unroll
        for (int p = 0; p < 4; ++p) pk[p] = f2bf(vv[p]);
        *(u16x4*)(outT + gc * ldT + grb) = pk;
      }
    }
  }
}

// --------------------------- GEMM 256x256 2-phase --------------------------
// LDS u16 layout per buffer (32768 u16 = 64KiB): A[kh 2][row 256][k 32] at 0,
// B[kh 2][row 256][k 32] at 16384. Two buffers (128KiB total).
// Swizzle: LDS slot s (8 u16 units within a 32-k half-row) holds global slot
// s ^ (row&3); staging pre-swizzles the global source, reads apply same XOR.
#define STAGE256(OP, KH, KZ, NB)                                                      \
  {                                                                                   \
    const u16* g_ = (OP) ? gB : gA;                                                   \
    const long ld_ = (OP) ? ldb : lda;                                                \
    u16* lb_ = lw + (NB) + (OP) * 16384 + (KH) * 8192;                                \
    __builtin_amdgcn_global_load_lds(AS1(g_ + (KZ) + (KH) * 32), AS3(lb_), 16, 0, 0); \
    __builtin_amdgcn_global_load_lds(AS1(g_ + (KZ) + (KH) * 32 + 128 * ld_),          \
                                     AS3(lb_ + 4096), 16, 0, 0);                      \
  }

#define LDA4(MH, KS, CB)                                                              \
  _Pragma("unroll") for (int i_ = 0; i_ < 4; ++i_)                                    \
      af[i_] = *(const bf16x8*)(smem + (CB) + (KS) * 8192 + abase + (MH) * 2048 + i_ * 512);

#define LDB4(KS, CB)                                                                  \
  _Pragma("unroll") for (int j_ = 0; j_ < 4; ++j_)                                    \
      bfr[j_] = *(const bf16x8*)(smem + (CB) + (KS) * 8192 + bbase + j_ * 512);

#define MFMA16(MH)                                                                    \
  _Pragma("unroll") for (int i_ = 0; i_ < 4; ++i_) {                                  \
    _Pragma("unroll") for (int j_ = 0; j_ < 4; ++j_) {                                \
      acc[(MH) * 4 + i_][j_] = __builtin_amdgcn_mfma_f32_16x16x32_bf16(               \
          af[i_], bfr[j_], acc[(MH) * 4 + i_][j_], 0, 0, 0);                          \
    }                                                                                 \
  }

__global__ __launch_bounds__(512, 2) void gemm256_2ph_kernel(
    const u16* __restrict__ A, long lda,
    const u16* __restrict__ Bt, long ldb,
    long K,
    const void* __restrict__ bias, int relu,
    void* __restrict__ outd, long odoff, long ldod,
    float* __restrict__ outw, long ldow, long ozstride,
    u16* __restrict__ outb, long ldob,
    const int* __restrict__ fl) {
  __shared__ u16 smem[65536];  // 128 KiB

  const int t = threadIdx.x;
  const int l = t & 63;
  const int w = t >> 6;
  const int wx = w & 3, wy = w >> 2;
  const int la = l & 15, lq = l >> 4;
  const long m0 = (long)blockIdx.y * 256;
  const long n0 = (long)blockIdx.x * 256;

  const long koff = (long)blockIdx.z * K;
  A += koff;
  Bt += koff;
  if (outw) outw += (long)blockIdx.z * ozstride;

  // staging coords: 512 threads, 4 threads/row (16B each), 128 rows/load-pair.
  const int sr = t >> 2;
  const long kc = 8 * ((t & 3) ^ (sr & 3));  // pre-swizzled k offset
  const u16* gA = A + (m0 + sr) * lda + kc;
  const u16* gB = Bt + (n0 + sr) * ldb + kc;
  u16* lw = smem + w * 512;  // wave-uniform stage base (lane writes +l*8)

  // fragment read offsets (u16 units), same XOR swizzle
  const int ard = la * 32 + ((lq ^ (la & 3)) << 3);
  const int abase = wy * 4096 + ard;          // + MH*2048 + i*512 + KS*8192 + CB
  const int bbase = 16384 + wx * 2048 + ard;  // + j*512 + KS*8192 + CB

  f32x4 acc[8][4];
  const f32x4 zero = {0.f, 0.f, 0.f, 0.f};
#pragma unroll
  for (int i = 0; i < 8; ++i)
#pragma unroll
    for (int j = 0; j < 4; ++j) acc[i][j] = zero;

  const long NT = K >> 6;

  // prologue: stage K-tile 0 into buffer 0
  STAGE256(0, 0, 0L, 0);
  STAGE256(1, 0, 0L, 0);
  STAGE256(0, 1, 0L, 0);
  STAGE256(1, 1, 0L, 0);
  __syncthreads();

  for (long kt = 0; kt < NT; ++kt) {
    const int cb = (int)(kt & 1) * 32768;
    if (kt + 1 < NT) {  // issue next-tile prefetch FIRST (flies during compute)
      const int nb = cb ^ 32768;
      const long kz = (kt + 1) << 6;
      STAGE256(0, 0, kz, nb);
      STAGE256(1, 0, kz, nb);
      STAGE256(0, 1, kz, nb);
      STAGE256(1, 1, kz, nb);
    }
    bf16x8 af[4], bfr[4];
    // ks=0
    LDB4(0, cb);
    LDA4(0, 0, cb);
    MFMA16(0);
    LDA4(1, 0, cb);
    MFMA16(1);
    // ks=1
    LDB4(1, cb);
    LDA4(0, 1, cb);
    MFMA16(0);
    LDA4(1, 1, cb);
    MFMA16(1);
    __syncthreads();  // drains vmcnt (next buffer resident) + lgkm + barrier
  }

  // epilogue
  const int dt = *fl;
  const long gr0 = m0 + wy * 128;
  const long gc0 = n0 + wx * 64;
#pragma unroll
  for (int gi = 0; gi < 8; ++gi) {
#pragma unroll
    for (int j = 0; j < 4; ++j) {
      const long gc = gc0 + j * 16 + la;
      const long grb = gr0 + gi * 16 + lq * 4;
      float bv = 0.f;
      if (bias) bv = dt ? bf2f(((const u16*)bias)[gc]) : ((const float*)bias)[gc];
      float vv[4];
#pragma unroll
      for (int p = 0; p < 4; ++p) {
        float x = acc[gi][j][p] + bv;
        if (relu) x = x > 0.f ? x : 0.f;
        vv[p] = x;
      }
      if (outd) {
        if (dt) {
          u16* o = (u16*)outd + odoff;
#pragma unroll
          for (int p = 0; p < 4; ++p) o[(grb + p) * ldod + gc] = f2bf(vv[p]);
        } else {
          float* o = (float*)outd + odoff;
#pragma unroll
          for (int p = 0; p < 4; ++p) o[(grb + p) * ldod + gc] = vv[p];
        }
      }
      if (outw) {
#pragma unroll
        for (int p = 0; p < 4; ++p) outw[(grb + p) * ldow + gc] = vv[p];
      }
      if (outb) {
#pragma unroll
        for (int p = 0; p < 4; ++p) outb[(grb + p) * ldob + gc] = f2bf(vv[p]);
      }
    }
  }
}

// --------------------------- host-side helpers -----------------------------
static void gemm(hipStream_t st, const u16* A, long lda, const u16* Bt, long ldb,
                 long M, long N, long K, int zsplit,
                 const void* bias, int relu,
                 void* outd, long odoff, long ldod,
                 float* outw, long ldow, long ozstride,
                 u16* outb, long ldob, u16* outb2, long ldob2,
                 u16* outT, long ldT, const int* fl) {
  dim3 g((unsigned)(N / 128), (unsigned)(M / 128), (unsigned)zsplit);
  gemm_bt_kernel<<<g, 256, 0, st>>>(A, lda, Bt, ldb, K, bias, relu, outd, odoff, ldod,
                                    outw, ldow, ozstride, outb, ldob, outb2, ldob2,
                                    outT, ldT, fl);
}

static void gemm256(hipStream_t st, const u16* A, long lda, const u16* Bt, long ldb,
                    long M, long N, long K,
                    const void* bias, int relu,
                    void* outd, long odoff, long ldod,
                    u16* outb, long ldob, const int* fl) {
  dim3 g((unsigned)(N / 256), (unsigned)(M / 256), 1);
  gemm256_2ph_kernel<<<g, 512, 0, st>>>(A, lda, Bt, ldb, K, bias, relu, outd, odoff, ldod,
                                        nullptr, 0, 0, outb, ldob, fl);
}

static void tconv(hipStream_t st, const void* src, long soff, u16* dst, int R, int C,
                  const int* fl) {
  tconv_kernel<<<dim3((unsigned)(C / 32), (unsigned)(R / 32)), 256, 0, st>>>(src, soff, dst, R,
                                                                             C, fl);
}

static void conv(hipStream_t st, const void* src, u16* dst, long n, const int* fl) {
  convert_kernel<<<(unsigned)((n / 8 + 255) / 256), 256, 0, st>>>(src, dst, n, fl);
}

extern "C" void kernel_launch(void* const* d_in, const int* in_sizes, int n_in,
                              void* d_out, int out_size, void* d_ws, size_t ws_size,
                              hipStream_t stream) {
  (void)in_sizes; (void)n_in; (void)out_size; (void)ws_size;
  const long NA = 16384, DEV = 4096, H1n = 1024, HD = 512, DM = 4096;

  char* ws = (char*)d_ws;
  // Workspace map (aliased; ~208 MiB total):
  u16* BIG = (u16*)(ws + 0L);               // 134.2 MB: bf16 H_M/H_A/H_D, then H_x^T
  u16* H1B = (u16*)(ws + 134217728L);       // 33.6 MB: hidden activations (bf16)
  float* SUMS = (float*)(ws + 134217728L);  // alias: split-K fp32 partials (4 x 2M)
  u16* HMT = (u16*)(ws + 167772160L);       // 16.8 MB: H_mean^T [512,16384] bf16
  u16* EVA = (u16*)(ws + 184549376L);       // 8.4 MB: EventA [4096,1024] bf16
  u16* EVD = (u16*)(ws + 192937984L);       // 8.4 MB: EventD
  u16* WT1 = (u16*)(ws + 201326592L);       // 8.4 MB: w1^T bf16 (per phase)
  u16* WT2 = (u16*)(ws + 209715200L);       // 8.4 MB: w2^T bf16 (per phase)
  int* FLAG = (int*)(ws + 218103808L);      // dtype flag

  const void* H_A = d_in[0];
  const void* H_D = d_in[1];
  const void* H_M = d_in[2];
  const void *wA1 = d_in[3], *bA1 = d_in[4], *wA2 = d_in[5], *bA2 = d_in[6];
  const void *wD1 = d_in[7], *bD1 = d_in[8], *wD2 = d_in[9], *bD2 = d_in[10];
  const void *wM1 = d_in[11], *bM1 = d_in[12], *wM2 = d_in[13], *bM2 = d_in[14];
  const void *wEA1 = d_in[15], *bEA1 = d_in[16], *wEA2 = d_in[17], *bEA2 = d_in[18];
  const void *wED1 = d_in[19], *bED1 = d_in[20], *wED2 = d_in[21], *bED2 = d_in[22];

  // d_out element offsets (return order): reconA, reconD, HmA, HmD, HmM
  const long O_RA = 0, O_RD = 16777216, O_HA = 33554432, O_HD = 41943040, O_HM = 50331648;

  detect_kernel<<<1, 64, 0, stream>>>((const u32*)H_A, FLAG);

  // ---------------- M phase: H_mean_M -> d_out + EventA/D[:, :512] ----------
  tconv(stream, wM1, 0, WT1, (int)DEV, (int)H1n, FLAG);  // [4096,1024] -> [1024,4096]
  tconv(stream, wM2, 0, WT2, (int)H1n, (int)HD, FLAG);   // [1024,512]  -> [512,1024]
  conv(stream, H_M, BIG, DEV * DEV, FLAG);
  gemm(stream, BIG, DEV, WT1, DEV, DEV, H1n, DEV, 1, bM1, 1,
       nullptr, 0, 0, nullptr, 0, 0, H1B, H1n, nullptr, 0, nullptr, 0, FLAG);
  gemm(stream, H1B, H1n, WT2, H1n, DEV, HD, H1n, 1, bM2, 0,
       d_out, O_HM, HD, nullptr, 0, 0, EVA, 1024, EVD, 1024, nullptr, 0, FLAG);

  // ---------------- A phase: H_mean_A, sum_A --------------------------------
  tconv(stream, wA1, 0, WT1, (int)DEV, (int)H1n, FLAG);
  tconv(stream, wA2, 0, WT2, (int)H1n, (int)HD, FLAG);
  conv(stream, H_A, BIG, NA * DEV, FLAG);
  gemm256(stream, BIG, DEV, WT1, DEV, NA, H1n, DEV, bA1, 1,
          nullptr, 0, 0, H1B, H1n, FLAG);
  gemm(stream, H1B, H1n, WT2, H1n, NA, HD, H1n, 1, bA2, 0,
       d_out, O_HA, HD, nullptr, 0, 0, nullptr, 0, nullptr, 0, HMT, NA, FLAG);
  // sum_A = H_A^T @ H_mean_A : transpose H_A into BIG, split-K=4 GEMM, reduce.
  tconv(stream, H_A, 0, BIG, (int)NA, (int)DEV, FLAG);  // BIG = H_A^T [4096,16384]
  gemm(stream, BIG, NA, HMT, NA, DEV, HD, 4096, 4, nullptr, 0,
       nullptr, 0, 0, SUMS, HD, 2097152L, nullptr, 0, nullptr, 0, nullptr, 0, FLAG);
  reduce4_kernel<<<8192, 256, 0, stream>>>(SUMS, 2097152L, EVA + 512, 1024L, DEV * HD, 9,
                                           nullptr, 0, FLAG);

  // ---------------- EA phase: reconstructA ----------------------------------
  tconv(stream, wEA1, 0, WT1, (int)H1n, (int)H1n, FLAG);
  tconv(stream, wEA2, 0, WT2, (int)H1n, (int)DM, FLAG);  // [1024,4096] -> [4096,1024]
  gemm(stream, EVA, 1024, WT1, H1n, DEV, H1n, H1n, 1, bEA1, 1,
       nullptr, 0, 0, nullptr, 0, 0, H1B, H1n, nullptr, 0, nullptr, 0, FLAG);
  gemm256(stream, H1B, H1n, WT2, H1n, DEV, DM, H1n, bEA2, 0,
          d_out, O_RA, DM, nullptr, 0, FLAG);

  // ---------------- D phase: H_mean_D, sum_D --------------------------------
  tconv(stream, wD1, 0, WT1, (int)DEV, (int)H1n, FLAG);
  tconv(stream, wD2, 0, WT2, (int)H1n, (int)HD, FLAG);
  conv(stream, H_D, BIG, NA * DEV, FLAG);
  gemm256(stream, BIG, DEV, WT1, DEV, NA, H1n, DEV, bD1, 1,
          nullptr, 0, 0, H1B, H1n, FLAG);
  gemm(stream, H1B, H1n, WT2, H1n, NA, HD, H1n, 1, bD2, 0,
       d_out, O_HD, HD, nullptr, 0, 0, nullptr, 0, nullptr, 0, HMT, NA, FLAG);
  tconv(stream, H_D, 0, BIG, (int)NA, (int)DEV, FLAG);  // BIG = H_D^T
  gemm(stream, BIG, NA, HMT, NA, DEV, HD, 4096, 4, nullptr, 0,
       nullptr, 0, 0, SUMS, HD, 2097152L, nullptr, 0, nullptr, 0, nullptr, 0, FLAG);
  reduce4_kernel<<<8192, 256, 0, stream>>>(SUMS, 2097152L, EVD + 512, 1024L, DEV * HD, 9,
                                           nullptr, 0, FLAG);

  // ---------------- ED phase: reconstructD ----------------------------------
  tconv(stream, wED1, 0, WT1, (int)H1n, (int)H1n, FLAG);
  tconv(stream, wED2, 0, WT2, (int)H1n, (int)DM, FLAG);
  gemm(stream, EVD, 1024, WT1, H1n, DEV, H1n, H1n, 1, bED1, 1,
       nullptr, 0, 0, nullptr, 0, 0, H1B, H1n, nullptr, 0, nullptr, 0, FLAG);
  gemm256(stream, H1B, H1n, WT2, H1n, DEV, DM, H1n, bED2, 0,
          d_out, O_RD, DM, nullptr, 0, FLAG);
}

// Round 4
// 1963.330 us; speedup vs baseline: 1.1346x; 1.0174x over previous
//
#include <hip/hip_runtime.h>
#include <cstdint>
#include <cstddef>

// ---------------------------------------------------------------------------
// myModel_ICDM: 5 two-layer MLPs + 2 pooling GEMMs, all as bf16 MFMA GEMMs.
// Two GEMM kernels, BOTH global_load_lds + __syncthreads only (no inline asm):
//  - gemm_bt_kernel: m97-style 128x128 tile.
//  - gemm256_2ph_kernel: 256x256 tile, BK=64, 8 waves, 128KiB LDS dbuf,
//    prefetch-issue-first 2-phase loop, XCD-bijective block swizzle.
// LDS swizzle (both): slot s of row r holds global k-slot s ^ ((r>>1)&3) —
// within each 8-lane b128 phase group, (row parity, slot) is a bijection over
// the 8 bank quads -> conflict-free (previous (r&3) XOR left 2-way).
// Routing: A1, D1, EA2, ED2, sumA(z=4), sumD(z=4) -> gemm256; rest -> gemm_bt.
// bf16 inputs: GEMMs read d_in raw (flag-selected), conv kernels early-exit.
// ---------------------------------------------------------------------------

typedef unsigned short u16;
typedef unsigned int u32;
typedef __bf16 bf16_t;
typedef bf16_t bf16x8 __attribute__((ext_vector_type(8)));
typedef float f32x4 __attribute__((ext_vector_type(4)));
typedef u16 u16x4 __attribute__((ext_vector_type(4)));
typedef u16 u16x8 __attribute__((ext_vector_type(8)));

__device__ __forceinline__ u16 f2bf(float x) {  // RNE fp32->bf16
  u32 u = __builtin_bit_cast(u32, x);
  u += 0x7FFFu + ((u >> 16) & 1u);
  return (u16)(u >> 16);
}
__device__ __forceinline__ float bf2f(u16 h) {
  u32 u = ((u32)h) << 16;
  return __builtin_bit_cast(float, u);
}

#define AS1(p) ((__attribute__((address_space(1))) void*)(p))
#define AS3(p) ((__attribute__((address_space(3))) void*)(p))

// --------------------------- dtype detection -------------------------------
__global__ void detect_kernel(const u32* __restrict__ p, int* __restrict__ flag) {
  if (threadIdx.x == 0 && blockIdx.x == 0) {
    int cnt = 0;
    for (int i = 0; i < 64; ++i) {
      u32 b = (p[i] >> 8) & 0xFFu;
      cnt += (b >= 0x3Au && b < 0x40u) ? 1 : 0;
    }
    *flag = (cnt >= 32) ? 1 : 0;  // 1 = bf16 inputs/outputs, 0 = fp32
  }
}

// --------------------------- convert (copy) --------------------------------
// skip!=0: when inputs are bf16 the GEMM reads d_in directly -> no-op.
__global__ void convert_kernel(const void* __restrict__ src, u16* __restrict__ dst,
                               long n, const int* __restrict__ fl, int skip) {
  const int dt = *fl;
  if (dt && skip) return;
  long i = ((long)blockIdx.x * 256 + threadIdx.x) * 8;
  if (i >= n) return;
  u16x8 r;
  if (dt) {
    r = *(const u16x8*)((const u16*)src + i);
  } else {
    const float* s = (const float*)src + i;
#pragma unroll
    for (int j = 0; j < 8; ++j) r[j] = f2bf(s[j]);
  }
  *(u16x8*)(dst + i) = r;
}

// --------------------------- transpose-convert -----------------------------
__global__ void tconv_kernel(const void* __restrict__ src, long soff, u16* __restrict__ dst,
                             int R, int C, const int* __restrict__ fl) {
  __shared__ u16 t[32][33];
  const int dt = *fl;
  const int tx = threadIdx.x & 31, ty = threadIdx.x >> 5;
  const long c0 = (long)blockIdx.x * 32, r0 = (long)blockIdx.y * 32;
#pragma unroll
  for (int r = 0; r < 4; ++r) {
    int rr = ty * 4 + r;
    long off = soff + (r0 + rr) * (long)C + c0 + tx;
    t[rr][tx] = dt ? ((const u16*)src)[off] : f2bf(((const float*)src)[off]);
  }
  __syncthreads();
#pragma unroll
  for (int r = 0; r < 4; ++r) {
    int rr = ty * 4 + r;
    dst[(c0 + rr) * (long)R + r0 + tx] = t[tx][rr];
  }
}

// --------------------------- split-K reduce --------------------------------
__global__ void reduce4_kernel(const float* __restrict__ s, long stride,
                               u16* __restrict__ dst, long ldd, long n, int cl,
                               const void* __restrict__ bias, int relu,
                               const int* __restrict__ fl) {
  long i = (long)blockIdx.x * 256 + threadIdx.x;
  if (i >= n) return;
  float v = s[i] + s[i + stride] + s[i + 2 * stride] + s[i + 3 * stride];
  long col = i & ((1L << cl) - 1);
  if (bias) v += (*fl) ? bf2f(((const u16*)bias)[col]) : ((const float*)bias)[col];
  if (relu) v = v > 0.f ? v : 0.f;
  dst[(i >> cl) * ldd + col] = f2bf(v);
}

// --------------------------- GEMM 128x128 (m97-style) ----------------------
__global__ __launch_bounds__(256) void gemm_bt_kernel(
    const u16* __restrict__ A, long lda,
    const u16* __restrict__ Bt, long ldb,
    long K,
    const void* __restrict__ bias, int relu,
    void* __restrict__ outd, long odoff, long ldod,
    float* __restrict__ outw, long ldow, long ozstride,
    u16* __restrict__ outb, long ldob,
    u16* __restrict__ outb2, long ldob2,
    u16* __restrict__ outT, long ldT,
    const void* __restrict__ rawA,
    const int* __restrict__ fl) {
  __shared__ u16 As[128 * 32];
  __shared__ u16 Bs[128 * 32];

  const int t = threadIdx.x;
  const int l = t & 63;
  const int w = t >> 6;
  const int wx = w & 1, wy = w >> 1;
  const long m0 = (long)blockIdx.y * 128;
  const long n0 = (long)blockIdx.x * 128;
  const int dt = *fl;
  if (dt && rawA) A = (const u16*)rawA;  // bf16 inputs: read source directly

  const long koff = (long)blockIdx.z * K;
  A += koff;
  Bt += koff;
  if (outw) outw += (long)blockIdx.z * ozstride;

  // staging: lane loads 16B; XOR k-slot swizzle (slot ^= (row>>1)&3).
  const int srow = w * 16 + (l >> 2);
  const int scol = ((l & 3) ^ ((l >> 3) & 3)) * 8;  // row bits 1,2 = (l>>3)&3
  const int la = l & 15, lq = l >> 4;
  const int fsl = (lq ^ ((la >> 1) & 3)) * 8;  // fragment-read swizzled slot

  f32x4 acc[4][4];
  const f32x4 zero = {0.f, 0.f, 0.f, 0.f};
#pragma unroll
  for (int i = 0; i < 4; ++i)
#pragma unroll
    for (int j = 0; j < 4; ++j) acc[i][j] = zero;

  for (long k0 = 0; k0 < K; k0 += 32) {
#pragma unroll
    for (int r = 0; r < 2; ++r) {
      const u16* ga = A + (m0 + r * 64 + srow) * lda + k0 + scol;
      __builtin_amdgcn_global_load_lds(AS1(ga), AS3(As + (r * 64 + w * 16) * 32), 16, 0, 0);
      const u16* gb = Bt + (n0 + r * 64 + srow) * ldb + k0 + scol;
      __builtin_amdgcn_global_load_lds(AS1(gb), AS3(Bs + (r * 64 + w * 16) * 32), 16, 0, 0);
    }
    __syncthreads();

    bf16x8 af[4], bfr[4];
#pragma unroll
    for (int i = 0; i < 4; ++i) {
      af[i] = *(const bf16x8*)(As + (wy * 64 + i * 16 + la) * 32 + fsl);
      bfr[i] = *(const bf16x8*)(Bs + (wx * 64 + i * 16 + la) * 32 + fsl);
    }
#pragma unroll
    for (int i = 0; i < 4; ++i)
#pragma unroll
      for (int j = 0; j < 4; ++j)
        acc[i][j] = __builtin_amdgcn_mfma_f32_16x16x32_bf16(af[i], bfr[j], acc[i][j], 0, 0, 0);
    __syncthreads();
  }

  const long gr0 = m0 + wy * 64;
  const long gc0 = n0 + wx * 64;
#pragma unroll
  for (int i = 0; i < 4; ++i) {
#pragma unroll
    for (int j = 0; j < 4; ++j) {
      const long gc = gc0 + j * 16 + la;
      const long grb = gr0 + i * 16 + lq * 4;
      float bv = 0.f;
      if (bias) bv = dt ? bf2f(((const u16*)bias)[gc]) : ((const float*)bias)[gc];
      float vv[4];
#pragma unroll
      for (int p = 0; p < 4; ++p) {
        float x = acc[i][j][p] + bv;
        if (relu) x = x > 0.f ? x : 0.f;
        vv[p] = x;
      }
      if (outd) {
        if (dt) {
          u16* o = (u16*)outd + odoff;
#pragma unroll
          for (int p = 0; p < 4; ++p) o[(grb + p) * ldod + gc] = f2bf(vv[p]);
        } else {
          float* o = (float*)outd + odoff;
#pragma unroll
          for (int p = 0; p < 4; ++p) o[(grb + p) * ldod + gc] = vv[p];
        }
      }
      if (outw) {
#pragma unroll
        for (int p = 0; p < 4; ++p) outw[(grb + p) * ldow + gc] = vv[p];
      }
      if (outb) {
#pragma unroll
        for (int p = 0; p < 4; ++p) outb[(grb + p) * ldob + gc] = f2bf(vv[p]);
      }
      if (outb2) {
#pragma unroll
        for (int p = 0; p < 4; ++p) outb2[(grb + p) * ldob2 + gc] = f2bf(vv[p]);
      }
      if (outT) {
        u16x4 pk;
#pragma unroll
        for (int p = 0; p < 4; ++p) pk[p] = f2bf(vv[p]);
        *(u16x4*)(outT + gc * ldT + grb) = pk;
      }
    }
  }
}

// --------------------------- GEMM 256x256 2-phase --------------------------
// LDS u16 layout per buffer (32768 u16 = 64KiB): A[kh 2][row 256][k 32] at 0,
// B[kh 2][row 256][k 32] at 16384. Two buffers (128KiB total).
// Swizzle: LDS slot s (8 u16 within a 32-k half-row) holds global slot
// s ^ ((row>>1)&3); staging pre-swizzles the global source.
#define STAGE256(OP, KH, KZ, NB)                                                      \
  {                                                                                   \
    const u16* g_ = (OP) ? gB : gA;                                                   \
    const long ld_ = (OP) ? ldb : lda;                                                \
    u16* lb_ = lw + (NB) + (OP) * 16384 + (KH) * 8192;                                \
    __builtin_amdgcn_global_load_lds(AS1(g_ + (KZ) + (KH) * 32), AS3(lb_), 16, 0, 0); \
    __builtin_amdgcn_global_load_lds(AS1(g_ + (KZ) + (KH) * 32 + 128 * ld_),          \
                                     AS3(lb_ + 4096), 16, 0, 0);                      \
  }

#define LDA4(MH, KS, CB)                                                              \
  _Pragma("unroll") for (int i_ = 0; i_ < 4; ++i_)                                    \
      af[i_] = *(const bf16x8*)(smem + (CB) + (KS) * 8192 + abase + (MH) * 2048 + i_ * 512);

#define LDB4(KS, CB)                                                                  \
  _Pragma("unroll") for (int j_ = 0; j_ < 4; ++j_)                                    \
      bfr[j_] = *(const bf16x8*)(smem + (CB) + (KS) * 8192 + bbase + j_ * 512);

#define MFMA16(MH)                                                                    \
  _Pragma("unroll") for (int i_ = 0; i_ < 4; ++i_) {                                  \
    _Pragma("unroll") for (int j_ = 0; j_ < 4; ++j_) {                                \
      acc[(MH) * 4 + i_][j_] = __builtin_amdgcn_mfma_f32_16x16x32_bf16(               \
          af[i_], bfr[j_], acc[(MH) * 4 + i_][j_], 0, 0, 0);                          \
    }                                                                                 \
  }

__global__ __launch_bounds__(512, 2) void gemm256_2ph_kernel(
    const u16* __restrict__ A, long lda,
    const u16* __restrict__ Bt, long ldb,
    long K,
    const void* __restrict__ bias, int relu,
    void* __restrict__ outd, long odoff, long ldod,
    float* __restrict__ outw, long ldow, long ozstride,
    u16* __restrict__ outb, long ldob,
    const void* __restrict__ rawA,
    const int* __restrict__ fl) {
  __shared__ u16 smem[65536];  // 128 KiB

  const int t = threadIdx.x;
  const int l = t & 63;
  const int w = t >> 6;
  const int wx = w & 3, wy = w >> 2;
  const int la = l & 15, lq = l >> 4;
  const int dt = *fl;
  if (dt && rawA) A = (const u16*)rawA;  // bf16 inputs: read source directly

  // XCD-bijective block swizzle (T1): XCD k owns a contiguous logical chunk;
  // within a chunk, n-blocks sharing an A-panel run consecutively.
  const unsigned gx = gridDim.x;
  const unsigned nwg = gx * gridDim.y;
  unsigned lx = blockIdx.x, ly = blockIdx.y;
  if ((nwg & 7u) == 0u) {
    const unsigned q = nwg >> 3;
    const unsigned L = ly * gx + lx;
    const unsigned nl = (L & 7u) * q + (L >> 3);
    lx = nl % gx;
    ly = nl / gx;
  }
  const long m0 = (long)ly * 256;
  const long n0 = (long)lx * 256;

  const long koff = (long)blockIdx.z * K;
  A += koff;
  Bt += koff;
  if (outw) outw += (long)blockIdx.z * ozstride;

  // staging coords: 512 threads, 4 threads/row (16B each), 128 rows/load-pair.
  const int sr = t >> 2;
  const long kc = 8 * ((t & 3) ^ ((sr >> 1) & 3));  // pre-swizzled k offset
  const u16* gA = A + (m0 + sr) * lda + kc;
  const u16* gB = Bt + (n0 + sr) * ldb + kc;
  u16* lw = smem + w * 512;  // wave-uniform stage base (lane writes +l*8)

  // fragment read offsets (u16 units), same XOR swizzle
  const int ard = la * 32 + ((lq ^ ((la >> 1) & 3)) << 3);
  const int abase = wy * 4096 + ard;          // + MH*2048 + i*512 + KS*8192 + CB
  const int bbase = 16384 + wx * 2048 + ard;  // + j*512 + KS*8192 + CB

  f32x4 acc[8][4];
  const f32x4 zero = {0.f, 0.f, 0.f, 0.f};
#pragma unroll
  for (int i = 0; i < 8; ++i)
#pragma unroll
    for (int j = 0; j < 4; ++j) acc[i][j] = zero;

  const long NT = K >> 6;

  // prologue: stage K-tile 0 into buffer 0
  STAGE256(0, 0, 0L, 0);
  STAGE256(1, 0, 0L, 0);
  STAGE256(0, 1, 0L, 0);
  STAGE256(1, 1, 0L, 0);
  __syncthreads();

  for (long kt = 0; kt < NT; ++kt) {
    const int cb = (int)(kt & 1) * 32768;
    if (kt + 1 < NT) {  // issue next-tile prefetch FIRST (flies during compute)
      const int nb = cb ^ 32768;
      const long kz = (kt + 1) << 6;
      STAGE256(0, 0, kz, nb);
      STAGE256(1, 0, kz, nb);
      STAGE256(0, 1, kz, nb);
      STAGE256(1, 1, kz, nb);
    }
    bf16x8 af[4], bfr[4];
    // ks=0
    LDB4(0, cb);
    LDA4(0, 0, cb);
    MFMA16(0);
    LDA4(1, 0, cb);
    MFMA16(1);
    // ks=1
    LDB4(1, cb);
    LDA4(0, 1, cb);
    MFMA16(0);
    LDA4(1, 1, cb);
    MFMA16(1);
    __syncthreads();  // drains vmcnt (next buffer resident) + lgkm + barrier
  }

  // epilogue
  const long gr0 = m0 + wy * 128;
  const long gc0 = n0 + wx * 64;
#pragma unroll
  for (int gi = 0; gi < 8; ++gi) {
#pragma unroll
    for (int j = 0; j < 4; ++j) {
      const long gc = gc0 + j * 16 + la;
      const long grb = gr0 + gi * 16 + lq * 4;
      float bv = 0.f;
      if (bias) bv = dt ? bf2f(((const u16*)bias)[gc]) : ((const float*)bias)[gc];
      float vv[4];
#pragma unroll
      for (int p = 0; p < 4; ++p) {
        float x = acc[gi][j][p] + bv;
        if (relu) x = x > 0.f ? x : 0.f;
        vv[p] = x;
      }
      if (outd) {
        if (dt) {
          u16* o = (u16*)outd + odoff;
#pragma unroll
          for (int p = 0; p < 4; ++p) o[(grb + p) * ldod + gc] = f2bf(vv[p]);
        } else {
          float* o = (float*)outd + odoff;
#pragma unroll
          for (int p = 0; p < 4; ++p) o[(grb + p) * ldod + gc] = vv[p];
        }
      }
      if (outw) {
#pragma unroll
        for (int p = 0; p < 4; ++p) outw[(grb + p) * ldow + gc] = vv[p];
      }
      if (outb) {
#pragma unroll
        for (int p = 0; p < 4; ++p) outb[(grb + p) * ldob + gc] = f2bf(vv[p]);
      }
    }
  }
}

// --------------------------- host-side helpers -----------------------------
static void gemm(hipStream_t st, const u16* A, long lda, const u16* Bt, long ldb,
                 long M, long N, long K, int zsplit,
                 const void* bias, int relu,
                 void* outd, long odoff, long ldod,
                 float* outw, long ldow, long ozstride,
                 u16* outb, long ldob, u16* outb2, long ldob2,
                 u16* outT, long ldT, const void* rawA, const int* fl) {
  dim3 g((unsigned)(N / 128), (unsigned)(M / 128), (unsigned)zsplit);
  gemm_bt_kernel<<<g, 256, 0, st>>>(A, lda, Bt, ldb, K, bias, relu, outd, odoff, ldod,
                                    outw, ldow, ozstride, outb, ldob, outb2, ldob2,
                                    outT, ldT, rawA, fl);
}

static void gemm256(hipStream_t st, const u16* A, long lda, const u16* Bt, long ldb,
                    long M, long N, long K, int zsplit,
                    const void* bias, int relu,
                    void* outd, long odoff, long ldod,
                    float* outw, long ldow, long ozstride,
                    u16* outb, long ldob, const void* rawA, const int* fl) {
  dim3 g((unsigned)(N / 256), (unsigned)(M / 256), (unsigned)zsplit);
  gemm256_2ph_kernel<<<g, 512, 0, st>>>(A, lda, Bt, ldb, K, bias, relu, outd, odoff, ldod,
                                        outw, ldow, ozstride, outb, ldob, rawA, fl);
}

static void tconv(hipStream_t st, const void* src, long soff, u16* dst, int R, int C,
                  const int* fl) {
  tconv_kernel<<<dim3((unsigned)(C / 32), (unsigned)(R / 32)), 256, 0, st>>>(src, soff, dst, R,
                                                                             C, fl);
}

static void conv(hipStream_t st, const void* src, u16* dst, long n, const int* fl, int skip) {
  convert_kernel<<<(unsigned)((n / 8 + 255) / 256), 256, 0, st>>>(src, dst, n, fl, skip);
}

extern "C" void kernel_launch(void* const* d_in, const int* in_sizes, int n_in,
                              void* d_out, int out_size, void* d_ws, size_t ws_size,
                              hipStream_t stream) {
  (void)in_sizes; (void)n_in; (void)out_size; (void)ws_size;
  const long NA = 16384, DEV = 4096, H1n = 1024, HD = 512, DM = 4096;

  char* ws = (char*)d_ws;
  // Workspace map (aliased; ~208 MiB total):
  u16* BIG = (u16*)(ws + 0L);               // 134.2 MB: bf16 (fp32 path) + H_x^T
  u16* H1B = (u16*)(ws + 134217728L);       // 33.6 MB: hidden activations (bf16)
  float* SUMS = (float*)(ws + 134217728L);  // alias: split-K fp32 partials (4 x 2M)
  u16* HMT = (u16*)(ws + 167772160L);       // 16.8 MB: H_mean^T [512,16384] bf16
  u16* EVA = (u16*)(ws + 184549376L);       // 8.4 MB: EventA [4096,1024] bf16
  u16* EVD = (u16*)(ws + 192937984L);       // 8.4 MB: EventD
  u16* WT1 = (u16*)(ws + 201326592L);       // 8.4 MB: w1^T bf16 (per phase)
  u16* WT2 = (u16*)(ws + 209715200L);       // 8.4 MB: w2^T bf16 (per phase)
  int* FLAG = (int*)(ws + 218103808L);      // dtype flag

  const void* H_A = d_in[0];
  const void* H_D = d_in[1];
  const void* H_M = d_in[2];
  const void *wA1 = d_in[3], *bA1 = d_in[4], *wA2 = d_in[5], *bA2 = d_in[6];
  const void *wD1 = d_in[7], *bD1 = d_in[8], *wD2 = d_in[9], *bD2 = d_in[10];
  const void *wM1 = d_in[11], *bM1 = d_in[12], *wM2 = d_in[13], *bM2 = d_in[14];
  const void *wEA1 = d_in[15], *bEA1 = d_in[16], *wEA2 = d_in[17], *bEA2 = d_in[18];
  const void *wED1 = d_in[19], *bED1 = d_in[20], *wED2 = d_in[21], *bED2 = d_in[22];

  // d_out element offsets (return order): reconA, reconD, HmA, HmD, HmM
  const long O_RA = 0, O_RD = 16777216, O_HA = 33554432, O_HD = 41943040, O_HM = 50331648;

  detect_kernel<<<1, 64, 0, stream>>>((const u32*)H_A, FLAG);

  // ---------------- M phase: H_mean_M -> d_out + EventA/D[:, :512] ----------
  tconv(stream, wM1, 0, WT1, (int)DEV, (int)H1n, FLAG);  // [4096,1024] -> [1024,4096]
  tconv(stream, wM2, 0, WT2, (int)H1n, (int)HD, FLAG);   // [1024,512]  -> [512,1024]
  conv(stream, H_M, BIG, DEV * DEV, FLAG, 1);            // no-op when bf16
  gemm(stream, BIG, DEV, WT1, DEV, DEV, H1n, DEV, 1, bM1, 1,
       nullptr, 0, 0, nullptr, 0, 0, H1B, H1n, nullptr, 0, nullptr, 0, H_M, FLAG);
  gemm(stream, H1B, H1n, WT2, H1n, DEV, HD, H1n, 1, bM2, 0,
       d_out, O_HM, HD, nullptr, 0, 0, EVA, 1024, EVD, 1024, nullptr, 0, nullptr, FLAG);

  // ---------------- A phase: H_mean_A, sum_A --------------------------------
  tconv(stream, wA1, 0, WT1, (int)DEV, (int)H1n, FLAG);
  tconv(stream, wA2, 0, WT2, (int)H1n, (int)HD, FLAG);
  conv(stream, H_A, BIG, NA * DEV, FLAG, 1);  // no-op when bf16
  gemm256(stream, BIG, DEV, WT1, DEV, NA, H1n, DEV, 1, bA1, 1,
          nullptr, 0, 0, nullptr, 0, 0, H1B, H1n, H_A, FLAG);
  gemm(stream, H1B, H1n, WT2, H1n, NA, HD, H1n, 1, bA2, 0,
       d_out, O_HA, HD, nullptr, 0, 0, nullptr, 0, nullptr, 0, HMT, NA, nullptr, FLAG);
  // sum_A = H_A^T @ H_mean_A : transpose H_A into BIG, split-K=4 GEMM, reduce.
  tconv(stream, H_A, 0, BIG, (int)NA, (int)DEV, FLAG);  // BIG = H_A^T [4096,16384]
  gemm256(stream, BIG, NA, HMT, NA, DEV, HD, 4096, 4, nullptr, 0,
          nullptr, 0, 0, SUMS, HD, 2097152L, nullptr, 0, nullptr, FLAG);
  reduce4_kernel<<<8192, 256, 0, stream>>>(SUMS, 2097152L, EVA + 512, 1024L, DEV * HD, 9,
                                           nullptr, 0, FLAG);

  // ---------------- EA phase: reconstructA ----------------------------------
  tconv(stream, wEA1, 0, WT1, (int)H1n, (int)H1n, FLAG);
  tconv(stream, wEA2, 0, WT2, (int)H1n, (int)DM, FLAG);  // [1024,4096] -> [4096,1024]
  gemm(stream, EVA, 1024, WT1, H1n, DEV, H1n, H1n, 1, bEA1, 1,
       nullptr, 0, 0, nullptr, 0, 0, H1B, H1n, nullptr, 0, nullptr, 0, nullptr, FLAG);
  gemm256(stream, H1B, H1n, WT2, H1n, DEV, DM, H1n, 1, bEA2, 0,
          d_out, O_RA, DM, nullptr, 0, 0, nullptr, 0, nullptr, FLAG);

  // ---------------- D phase: H_mean_D, sum_D --------------------------------
  tconv(stream, wD1, 0, WT1, (int)DEV, (int)H1n, FLAG);
  tconv(stream, wD2, 0, WT2, (int)H1n, (int)HD, FLAG);
  conv(stream, H_D, BIG, NA * DEV, FLAG, 1);  // no-op when bf16
  gemm256(stream, BIG, DEV, WT1, DEV, NA, H1n, DEV, 1, bD1, 1,
          nullptr, 0, 0, nullptr, 0, 0, H1B, H1n, H_D, FLAG);
  gemm(stream, H1B, H1n, WT2, H1n, NA, HD, H1n, 1, bD2, 0,
       d_out, O_HD, HD, nullptr, 0, 0, nullptr, 0, nullptr, 0, HMT, NA, nullptr, FLAG);
  tconv(stream, H_D, 0, BIG, (int)NA, (int)DEV, FLAG);  // BIG = H_D^T
  gemm256(stream, BIG, NA, HMT, NA, DEV, HD, 4096, 4, nullptr, 0,
          nullptr, 0, 0, SUMS, HD, 2097152L, nullptr, 0, nullptr, FLAG);
  reduce4_kernel<<<8192, 256, 0, stream>>>(SUMS, 2097152L, EVD + 512, 1024L, DEV * HD, 9,
                                           nullptr, 0, FLAG);

  // ---------------- ED phase: reconstructD ----------------------------------
  tconv(stream, wED1, 0, WT1, (int)H1n, (int)H1n, FLAG);
  tconv(stream, wED2, 0, WT2, (int)H1n, (int)DM, FLAG);
  gemm(stream, EVD, 1024, WT1, H1n, DEV, H1n, H1n, 1, bED1, 1,
       nullptr, 0, 0, nullptr, 0, 0, H1B, H1n, nullptr, 0, nullptr, 0, nullptr, FLAG);
  gemm256(stream, H1B, H1n, WT2, H1n, DEV, DM, H1n, 1, bED2, 0,
          d_out, O_RD, DM, nullptr, 0, 0, nullptr, 0, nullptr, FLAG);
}